// Round 1
// baseline (2296.297 us; speedup 1.0000x reference)
//
#include <hip/hip_runtime.h>

// ---------- types ----------
typedef __attribute__((ext_vector_type(8))) short bf16x8;   // 8 bf16 in 4 VGPRs
typedef __attribute__((ext_vector_type(4))) float f32x4;

// ---------- bf16 helpers (RNE, bit-level; values are tame, no NaN path) ----------
__device__ __forceinline__ short f2bf(float f) {
    union { float f; unsigned u; } v; v.f = f;
    unsigned r = v.u + 0x7fffu + ((v.u >> 16) & 1u);
    return (short)(r >> 16);
}
__device__ __forceinline__ float bf2f(short s) {
    union { unsigned u; float f; } v; v.u = ((unsigned)(unsigned short)s) << 16;
    return v.f;
}
__device__ __forceinline__ unsigned pack2(float x, float y) {
    return (unsigned)(unsigned short)f2bf(x) | ((unsigned)(unsigned short)f2bf(y) << 16);
}
__device__ __forceinline__ uint4 pack8(float4 a, float4 b) {
    return make_uint4(pack2(a.x, a.y), pack2(a.z, a.w), pack2(b.x, b.y), pack2(b.z, b.w));
}

// ---------- prep: Wcat bf16 [1024][2048] = [W_ih | W_hh] (K-major rows) ----------
__global__ void prep_w(const float* __restrict__ W_ih, const float* __restrict__ W_hh,
                       short* __restrict__ Wcat) {
    int i = blockIdx.x * 256 + threadIdx.x;     // 0..262143, 8 elems each
    int idx = i * 8;
    int n = idx >> 11, k = idx & 2047;
    const float* src = (k < 1024) ? (W_ih + n * 1024 + k) : (W_hh + n * 1024 + (k - 1024));
    float4 f0 = ((const float4*)src)[0];
    float4 f1 = ((const float4*)src)[1];
    *(uint4*)(Wcat + idx) = pack8(f0, f1);
}

__global__ void prep_b(const float* __restrict__ b_ih, const float* __restrict__ b_hh,
                       float* __restrict__ bsum) {
    int n = threadIdx.x;                         // one block of 1024
    bsum[n] = b_ih[n] + b_hh[n];
}

// ---------- fused RNN step: h' = tanh([x_t | h] * Wcat^T + bsum) ----------
// Tile: 64x64, BK=64, 256 threads (4 waves, each 32x32 via 2x2 mfma 16x16x32 bf16)
#define LDK 80   // padded K stride (elems): 160B rows -> 16B-aligned b128, 2-way banks (free)

__device__ __forceinline__ void load_a(const float* __restrict__ av,
                                       const short* __restrict__ h_in,
                                       int t, int gr, int k, uint4& r0, uint4& r1) {
    if (k < 1024) {  // x part: fp32 av[b][t][k..k+15] -> bf16
        const float* src = av + ((size_t)gr << 16) + t * 1024 + k;
        float4 f0 = ((const float4*)src)[0];
        float4 f1 = ((const float4*)src)[1];
        float4 f2 = ((const float4*)src)[2];
        float4 f3 = ((const float4*)src)[3];
        r0 = pack8(f0, f1);
        r1 = pack8(f2, f3);
    } else {        // h part: already bf16
        const uint4* src = (const uint4*)(h_in + (size_t)gr * 1024 + (k - 1024));
        r0 = src[0];
        r1 = src[1];
    }
}

__global__ __launch_bounds__(256) void step_kernel(
    const float* __restrict__ av, const short* __restrict__ Wcat,
    const float* __restrict__ bsum, const short* __restrict__ h_in,
    short* __restrict__ h_out, int t, int kIters) {
    __shared__ short As[64 * LDK];
    __shared__ short Bs[64 * LDK];

    const int tid  = threadIdx.x;
    const int m0   = blockIdx.y * 64;   // batch rows
    const int n0   = blockIdx.x * 64;   // hidden cols
    const int lane = tid & 63, wave = tid >> 6;
    const int wm   = wave >> 1, wn = wave & 1;
    const int srow = tid >> 2, sq = tid & 3;    // staging: row 0..63, 16 elems at sq*16
    const int scol = sq * 16;
    const int gr   = m0 + srow;                 // global batch row for A staging
    const int gn   = n0 + srow;                 // global weight row for B staging

    uint4 ra0, ra1, rb0, rb1;
    load_a(av, h_in, t, gr, scol, ra0, ra1);
    {
        const uint4* src = (const uint4*)(Wcat + (size_t)gn * 2048 + scol);
        rb0 = src[0]; rb1 = src[1];
    }

    f32x4 acc[2][2];
    #pragma unroll
    for (int i = 0; i < 2; i++)
        #pragma unroll
        for (int j = 0; j < 2; j++) acc[i][j] = (f32x4)0.0f;

    const int arow = wm * 32 + (lane & 15);
    const int brow = wn * 32 + (lane & 15);
    const int koff = (lane >> 4) * 8;

    for (int kt = 0; kt < kIters; ++kt) {
        uint4* pa = (uint4*)&As[srow * LDK + scol];
        pa[0] = ra0; pa[1] = ra1;
        uint4* pb = (uint4*)&Bs[srow * LDK + scol];
        pb[0] = rb0; pb[1] = rb1;
        __syncthreads();

        if (kt + 1 < kIters) {                    // prefetch next K-tile (hides VMEM latency)
            int k = (kt + 1) * 64 + scol;
            load_a(av, h_in, t, gr, k, ra0, ra1);
            const uint4* src = (const uint4*)(Wcat + (size_t)gn * 2048 + k);
            rb0 = src[0]; rb1 = src[1];
        }

        #pragma unroll
        for (int ks = 0; ks < 2; ++ks) {
            bf16x8 a0 = *(const bf16x8*)&As[arow * LDK + ks * 32 + koff];
            bf16x8 a1 = *(const bf16x8*)&As[(arow + 16) * LDK + ks * 32 + koff];
            bf16x8 b0 = *(const bf16x8*)&Bs[brow * LDK + ks * 32 + koff];
            bf16x8 b1 = *(const bf16x8*)&Bs[(brow + 16) * LDK + ks * 32 + koff];
            acc[0][0] = __builtin_amdgcn_mfma_f32_16x16x32_bf16(a0, b0, acc[0][0], 0, 0, 0);
            acc[0][1] = __builtin_amdgcn_mfma_f32_16x16x32_bf16(a0, b1, acc[0][1], 0, 0, 0);
            acc[1][0] = __builtin_amdgcn_mfma_f32_16x16x32_bf16(a1, b0, acc[1][0], 0, 0, 0);
            acc[1][1] = __builtin_amdgcn_mfma_f32_16x16x32_bf16(a1, b1, acc[1][1], 0, 0, 0);
        }
        __syncthreads();
    }

    // epilogue: C layout col = lane&15, row = quad*4 + r  (m89/m91-verified)
    const int quad = lane >> 4;
    #pragma unroll
    for (int mi = 0; mi < 2; mi++) {
        #pragma unroll
        for (int ni = 0; ni < 2; ni++) {
            int n  = n0 + wn * 32 + ni * 16 + (lane & 15);
            int mb = m0 + wm * 32 + mi * 16 + quad * 4;
            float bs = bsum[n];
            #pragma unroll
            for (int r = 0; r < 4; r++) {
                float v = acc[mi][ni][r] + bs;
                h_out[(size_t)(mb + r) * 1024 + n] = f2bf(tanhf(v));
            }
        }
    }
}

// ---------- head: p[b] = sigmoid(h . W_out + b_out), wave-per-row ----------
__global__ __launch_bounds__(256) void head_kernel(const short* __restrict__ h,
                                                   const float* __restrict__ W_out,
                                                   const float* __restrict__ b_out,
                                                   float* __restrict__ p) {
    int b    = blockIdx.x * 4 + (threadIdx.x >> 6);
    int lane = threadIdx.x & 63;
    float s = 0.f;
    for (int k = lane; k < 1024; k += 64)
        s += bf2f(h[(size_t)b * 1024 + k]) * W_out[k];
    #pragma unroll
    for (int off = 32; off > 0; off >>= 1) s += __shfl_down(s, off);
    if (lane == 0) p[b] = 1.f / (1.f + expf(-(s + b_out[0])));
}

// ---------- loss: BCE mean with torch-style log clamp at -100 ----------
__global__ __launch_bounds__(1024) void loss_kernel(const float* __restrict__ p,
                                                    const float* __restrict__ y,
                                                    float* __restrict__ loss) {
    __shared__ float red[1024];
    int b = threadIdx.x;
    float pv = p[b];
    float yb = (y[b] >= 1e-5f) ? 1.f : 0.f;
    float lp  = fmaxf(logf(pv), -100.f);
    float l1  = fmaxf(log1pf(-pv), -100.f);
    red[b] = yb * lp + (1.f - yb) * l1;
    __syncthreads();
    for (int s = 512; s > 0; s >>= 1) {
        if (b < s) red[b] += red[b + s];
        __syncthreads();
    }
    if (b == 0) loss[0] = -red[0] / 1024.f;
}

// ---------- launch ----------
extern "C" void kernel_launch(void* const* d_in, const int* in_sizes, int n_in,
                              void* d_out, int out_size, void* d_ws, size_t ws_size,
                              hipStream_t stream) {
    // inputs: 0 ui, 1 uv, 2 ai (unused), 3 av, 4 y, 5 W_ih, 6 b_ih, 7 W_hh, 8 b_hh,
    //         9 W_out, 10 b_out
    const float* av    = (const float*)d_in[3];
    const float* y     = (const float*)d_in[4];
    const float* W_ih  = (const float*)d_in[5];
    const float* b_ih  = (const float*)d_in[6];
    const float* W_hh  = (const float*)d_in[7];
    const float* b_hh  = (const float*)d_in[8];
    const float* W_out = (const float*)d_in[9];
    const float* b_out = (const float*)d_in[10];
    float* out = (float*)d_out;                  // [0]=loss, [1..1024]=p

    char* ws = (char*)d_ws;
    short* Wcat = (short*)ws;                    // 4 MB bf16 [1024][2048]
    short* h0b  = (short*)(ws + (4u << 20));     // 2 MB bf16 h buffer A
    short* h1b  = (short*)(ws + (6u << 20));     // 2 MB bf16 h buffer B
    float* bsum = (float*)(ws + (8u << 20));     // 4 KB

    prep_w<<<1024, 256, 0, stream>>>(W_ih, W_hh, Wcat);
    prep_b<<<1, 1024, 0, stream>>>(b_ih, b_hh, bsum);

    short* hbuf[2] = { h0b, h1b };
    for (int t = 0; t < 64; ++t) {
        short* hin  = hbuf[t & 1];               // unused at t=0 (kIters=16 skips h half)
        short* hout = hbuf[(t + 1) & 1];
        step_kernel<<<dim3(16, 16), 256, 0, stream>>>(av, Wcat, bsum, hin, hout, t,
                                                      (t == 0) ? 16 : 32);
    }
    // final h is in hbuf[0] (t=63 writes buf[(64)&1] = buf[0])
    head_kernel<<<256, 256, 0, stream>>>(hbuf[0], W_out, b_out, out + 1);
    loss_kernel<<<1, 1024, 0, stream>>>(out + 1, y, out);
}

// Round 3
// 1711.013 us; speedup vs baseline: 1.3421x; 1.3421x over previous
//
#include <hip/hip_runtime.h>

// ---------- types ----------
typedef __attribute__((ext_vector_type(8))) short bf16x8;   // 8 bf16 in 4 VGPRs
typedef __attribute__((ext_vector_type(4))) float f32x4;

// ---------- bf16 helpers (RNE, bit-level) ----------
__device__ __forceinline__ short f2bf(float f) {
    union { float f; unsigned u; } v; v.f = f;
    unsigned r = v.u + 0x7fffu + ((v.u >> 16) & 1u);
    return (short)(r >> 16);
}
__device__ __forceinline__ float bf2f(short s) {
    union { unsigned u; float f; } v; v.u = ((unsigned)(unsigned short)s) << 16;
    return v.f;
}
__device__ __forceinline__ unsigned pack2(float x, float y) {
    return (unsigned)(unsigned short)f2bf(x) | ((unsigned)(unsigned short)f2bf(y) << 16);
}
__device__ __forceinline__ uint4 pack8(float4 a, float4 b) {
    return make_uint4(pack2(a.x, a.y), pack2(a.z, a.w), pack2(b.x, b.y), pack2(b.z, b.w));
}
__device__ __forceinline__ float tanh_fast(float x) {
    float e = __expf(2.f * x);
    return 1.f - 2.f / (e + 1.f);
}

// ---------- prep: fp32 [1024][1024] -> bf16 ----------
__global__ __launch_bounds__(256) void pack_w(const float* __restrict__ src,
                                              short* __restrict__ dst) {
    int idx = (blockIdx.x * 256 + threadIdx.x) * 8;
    float4 f0 = ((const float4*)(src + idx))[0];
    float4 f1 = ((const float4*)(src + idx))[1];
    *(uint4*)(dst + idx) = pack8(f0, f1);
}

__global__ void prep_b(const float* __restrict__ b_ih, const float* __restrict__ b_hh,
                       float* __restrict__ bsum) {
    int n = threadIdx.x;
    bsum[n] = b_ih[n] + b_hh[n];
}

// ---------- big parallel GEMM: Z[t][b][n] = bf16(av . W_ih^T + bsum) ----------
// M = T*B = 65536 (row r = t*1024 + b), K = 1024, N = 1024
// 128x128 tile, BK=64, 256 thr (4 waves 2x2, wave tile 64x64), reg-prefetch staging
#define ZLDK 72   // padded K stride (elems); 144B rows: 16B-aligned, balanced banks

__global__ __launch_bounds__(256) void zgemm(const float* __restrict__ av,
                                             const short* __restrict__ Wih,
                                             const float* __restrict__ bsum,
                                             short* __restrict__ Z) {
    __shared__ short As[128 * ZLDK];
    __shared__ short Bs[128 * ZLDK];

    const int tid = threadIdx.x, lane = tid & 63, wave = tid >> 6;
    const int wm = wave >> 1, wn = wave & 1;
    const int m0 = blockIdx.y * 128, n0 = blockIdx.x * 128;
    const int srow = tid >> 1, scol = (tid & 1) * 32;

    // A source: row gr = t*1024+b of x; av[b][t][k]
    const int gr = m0 + srow;
    const int tt = gr >> 10, bb = gr & 1023;
    const float* asrc = av + ((size_t)bb * 64 + tt) * 1024 + scol;
    const short* bsrc = Wih + (size_t)(n0 + srow) * 1024 + scol;

    uint4 ra[4], rb[4];
    #pragma unroll
    for (int j = 0; j < 4; j++) {
        float4 f0 = *(const float4*)(asrc + 8 * j);
        float4 f1 = *(const float4*)(asrc + 8 * j + 4);
        ra[j] = pack8(f0, f1);
        rb[j] = *(const uint4*)(bsrc + 8 * j);
    }

    f32x4 acc[4][4];
    #pragma unroll
    for (int i = 0; i < 4; i++)
        #pragma unroll
        for (int j = 0; j < 4; j++) acc[i][j] = (f32x4)0.0f;

    const int r = lane & 15, q = lane >> 4;
    const int koff = q * 8;

    for (int kt = 0; kt < 16; ++kt) {
        #pragma unroll
        for (int j = 0; j < 4; j++) {
            *(uint4*)&As[srow * ZLDK + scol + 8 * j] = ra[j];
            *(uint4*)&Bs[srow * ZLDK + scol + 8 * j] = rb[j];
        }
        __syncthreads();

        if (kt < 15) {
            int k = (kt + 1) * 64;
            #pragma unroll
            for (int j = 0; j < 4; j++) {
                float4 f0 = *(const float4*)(asrc + k + 8 * j);
                float4 f1 = *(const float4*)(asrc + k + 8 * j + 4);
                ra[j] = pack8(f0, f1);
                rb[j] = *(const uint4*)(bsrc + k + 8 * j);
            }
        }

        #pragma unroll
        for (int ks = 0; ks < 2; ++ks) {
            bf16x8 af[4], bfr[4];
            #pragma unroll
            for (int i = 0; i < 4; i++) {
                af[i]  = *(const bf16x8*)&As[(wm * 64 + i * 16 + r) * ZLDK + ks * 32 + koff];
                bfr[i] = *(const bf16x8*)&Bs[(wn * 64 + i * 16 + r) * ZLDK + ks * 32 + koff];
            }
            #pragma unroll
            for (int i = 0; i < 4; i++)
                #pragma unroll
                for (int j = 0; j < 4; j++)
                    acc[i][j] = __builtin_amdgcn_mfma_f32_16x16x32_bf16(af[i], bfr[j], acc[i][j], 0, 0, 0);
        }
        __syncthreads();
    }

    // epilogue: C layout col = lane&15, row = quad*4 + rr; Z flat = row*1024 + n
    #pragma unroll
    for (int j = 0; j < 4; j++) {
        int n = n0 + wn * 64 + j * 16 + r;
        float bs = bsum[n];
        #pragma unroll
        for (int i = 0; i < 4; i++) {
            int mb = m0 + wm * 64 + i * 16 + q * 4;
            #pragma unroll
            for (int rr = 0; rr < 4; rr++)
                Z[(size_t)(mb + rr) * 1024 + n] = f2bf(acc[i][j][rr] + bs);
        }
    }
}

// ---------- t=0: h1 = tanh(Z[0]) elementwise ----------
__global__ __launch_bounds__(256) void t0_kernel(const short* __restrict__ Z,
                                                 short* __restrict__ h) {
    int idx = (blockIdx.x * 256 + threadIdx.x) * 8;
    uint4 zv = *(const uint4*)(Z + idx);
    const unsigned* zp = (const unsigned*)&zv;
    uint4 out;
    unsigned* op = (unsigned*)&out;
    #pragma unroll
    for (int j = 0; j < 4; j++) {
        float lo = tanh_fast(bf2f((short)(zp[j] & 0xffffu)));
        float hi = tanh_fast(bf2f((short)(zp[j] >> 16)));
        op[j] = pack2(lo, hi);
    }
    *(uint4*)(h + idx) = out;
}

// ---------- RNN step t>=1: h' = tanh(h . W_hh^T + Z[t]) ----------
// 64x64 tile, grid 16x16, 512 thr (8 waves 2x4, wave tile 32x16), BK=128 reg-prefetch
// Staging: 8 threads per row, each owns a 16-elem slot -> loads TWO uint4s (r2 bugfix)
#define SLDK 136  // padded K stride: 272B rows, 16B-aligned

__global__ __launch_bounds__(512) void step_kernel(const short* __restrict__ Whh,
                                                   const short* __restrict__ Z,
                                                   const short* __restrict__ h_in,
                                                   short* __restrict__ h_out, int t) {
    __shared__ short As[64 * SLDK];
    __shared__ short Bs[64 * SLDK];

    const int tid = threadIdx.x, lane = tid & 63, wave = tid >> 6;
    const int wm = wave >> 2, wn = wave & 3;
    const int m0 = blockIdx.y * 64, n0 = blockIdx.x * 64;
    const int srow = tid >> 3, scol = (tid & 7) * 16;

    const short* asrc = h_in + (size_t)(m0 + srow) * 1024 + scol;
    const short* bsrc = Whh + (size_t)(n0 + srow) * 1024 + scol;

    uint4 ra0 = *(const uint4*)asrc;
    uint4 ra1 = *(const uint4*)(asrc + 8);
    uint4 rb0 = *(const uint4*)bsrc;
    uint4 rb1 = *(const uint4*)(bsrc + 8);

    f32x4 acc[2];
    acc[0] = (f32x4)0.0f;
    acc[1] = (f32x4)0.0f;

    const int r = lane & 15, q = lane >> 4;
    const int arow = wm * 32 + r, brow = wn * 16 + r;
    const int koff = q * 8;

    for (int chunk = 0; chunk < 8; ++chunk) {
        *(uint4*)&As[srow * SLDK + scol]     = ra0;
        *(uint4*)&As[srow * SLDK + scol + 8] = ra1;
        *(uint4*)&Bs[srow * SLDK + scol]     = rb0;
        *(uint4*)&Bs[srow * SLDK + scol + 8] = rb1;
        __syncthreads();

        if (chunk < 7) {
            int k = (chunk + 1) * 128;
            ra0 = *(const uint4*)(asrc + k);
            ra1 = *(const uint4*)(asrc + k + 8);
            rb0 = *(const uint4*)(bsrc + k);
            rb1 = *(const uint4*)(bsrc + k + 8);
        }

        #pragma unroll
        for (int ks = 0; ks < 4; ++ks) {
            bf16x8 a0 = *(const bf16x8*)&As[arow * SLDK + ks * 32 + koff];
            bf16x8 a1 = *(const bf16x8*)&As[(arow + 16) * SLDK + ks * 32 + koff];
            bf16x8 b  = *(const bf16x8*)&Bs[brow * SLDK + ks * 32 + koff];
            acc[0] = __builtin_amdgcn_mfma_f32_16x16x32_bf16(a0, b, acc[0], 0, 0, 0);
            acc[1] = __builtin_amdgcn_mfma_f32_16x16x32_bf16(a1, b, acc[1], 0, 0, 0);
        }
        __syncthreads();
    }

    // epilogue: add Z[t], tanh, write bf16
    const short* zt = Z + ((size_t)t << 20);
    int n = n0 + wn * 16 + r;
    #pragma unroll
    for (int mi = 0; mi < 2; mi++) {
        int mb = m0 + wm * 32 + mi * 16 + q * 4;
        #pragma unroll
        for (int rr = 0; rr < 4; rr++) {
            float z = bf2f(zt[((size_t)(mb + rr) << 10) + n]);
            h_out[((size_t)(mb + rr) << 10) + n] = f2bf(tanh_fast(acc[mi][rr] + z));
        }
    }
}

// ---------- head: p[b] = sigmoid(h . W_out + b_out), wave-per-row ----------
__global__ __launch_bounds__(256) void head_kernel(const short* __restrict__ h,
                                                   const float* __restrict__ W_out,
                                                   const float* __restrict__ b_out,
                                                   float* __restrict__ p) {
    int b    = blockIdx.x * 4 + (threadIdx.x >> 6);
    int lane = threadIdx.x & 63;
    float s = 0.f;
    for (int k = lane; k < 1024; k += 64)
        s += bf2f(h[(size_t)b * 1024 + k]) * W_out[k];
    #pragma unroll
    for (int off = 32; off > 0; off >>= 1) s += __shfl_down(s, off);
    if (lane == 0) p[b] = 1.f / (1.f + __expf(-(s + b_out[0])));
}

// ---------- loss: BCE mean with torch-style log clamp at -100 ----------
__global__ __launch_bounds__(1024) void loss_kernel(const float* __restrict__ p,
                                                    const float* __restrict__ y,
                                                    float* __restrict__ loss) {
    __shared__ float red[1024];
    int b = threadIdx.x;
    float pv = p[b];
    float yb = (y[b] >= 1e-5f) ? 1.f : 0.f;
    float lp = fmaxf(logf(pv), -100.f);
    float l1 = fmaxf(log1pf(-pv), -100.f);
    red[b] = yb * lp + (1.f - yb) * l1;
    __syncthreads();
    for (int s = 512; s > 0; s >>= 1) {
        if (b < s) red[b] += red[b + s];
        __syncthreads();
    }
    if (b == 0) loss[0] = -red[0] / 1024.f;
}

// ---------- launch ----------
extern "C" void kernel_launch(void* const* d_in, const int* in_sizes, int n_in,
                              void* d_out, int out_size, void* d_ws, size_t ws_size,
                              hipStream_t stream) {
    const float* av    = (const float*)d_in[3];
    const float* y     = (const float*)d_in[4];
    const float* W_ih  = (const float*)d_in[5];
    const float* b_ih  = (const float*)d_in[6];
    const float* W_hh  = (const float*)d_in[7];
    const float* b_hh  = (const float*)d_in[8];
    const float* W_out = (const float*)d_in[9];
    const float* b_out = (const float*)d_in[10];
    float* out = (float*)d_out;                      // [0]=loss, [1..1024]=p

    char* ws = (char*)d_ws;
    short* Wih_bf = (short*)ws;                      // 2 MB
    short* Whh_bf = (short*)(ws + (2u << 20));       // 2 MB
    float* bsum   = (float*)(ws + (4u << 20));       // 4 KB
    short* hb0    = (short*)(ws + (5u << 20));       // 2 MB
    short* hb1    = (short*)(ws + (7u << 20));       // 2 MB
    short* Z      = (short*)(ws + (9u << 20));       // 128 MB: [64][1024][1024] bf16

    pack_w<<<512, 256, 0, stream>>>(W_ih, Wih_bf);
    pack_w<<<512, 256, 0, stream>>>(W_hh, Whh_bf);
    prep_b<<<1, 1024, 0, stream>>>(b_ih, b_hh, bsum);

    zgemm<<<dim3(8, 512), 256, 0, stream>>>(av, Wih_bf, bsum, Z);

    short* hbuf[2] = { hb0, hb1 };
    t0_kernel<<<512, 256, 0, stream>>>(Z, hb1);      // h_1 = tanh(Z[0])
    for (int t = 1; t < 64; ++t) {
        short* hin  = hbuf[t & 1];
        short* hout = hbuf[(t + 1) & 1];
        step_kernel<<<dim3(16, 16), 512, 0, stream>>>(Whh_bf, Z, hin, hout, t);
    }
    // t=63 writes hbuf[0]
    head_kernel<<<256, 256, 0, stream>>>(hb0, W_out, b_out, out + 1);
    loss_kernel<<<1, 1024, 0, stream>>>(out + 1, y, out);
}